// Round 4
// baseline (547.992 us; speedup 1.0000x reference)
//
#include <hip/hip_runtime.h>
#include <hip/hip_fp16.h>

// Problem constants (B=2, P=64, N=256, C=512, H=8, D=64)
#define BP   128
#define NTOK 256
#define CDIM 512
#define ROWS 32768   // BP*NTOK
#define NH   8
#define DH   64

typedef _Float16 h2_t __attribute__((ext_vector_type(2)));
typedef _Float16 h4_t __attribute__((ext_vector_type(4)));
typedef _Float16 h8_t __attribute__((ext_vector_type(8)));
typedef float    f4_t __attribute__((ext_vector_type(4)));

// async global->LDS, 16B per lane. LDS dest = wave-uniform base + lane*16.
__device__ __forceinline__ void async16(const void* gptr, void* lptr) {
    __builtin_amdgcn_global_load_lds(
        (const __attribute__((address_space(1))) unsigned int*)gptr,
        (__attribute__((address_space(3))) unsigned int*)lptr, 16, 0, 0);
}

// ---------------------------------------------------------------------------
// LayerNorm + cast to fp16. One wave per row of 512.
// ---------------------------------------------------------------------------
__global__ __launch_bounds__(256) void ln_cast(const float* __restrict__ x,
                                               const float* __restrict__ g,
                                               const float* __restrict__ b,
                                               _Float16* __restrict__ y) {
    const int wave = threadIdx.x >> 6, lane = threadIdx.x & 63;
    const size_t row = (size_t)blockIdx.x * 4 + wave;
    const float4* xr = (const float4*)(x + row * CDIM);
    float4 a0 = xr[2 * lane], a1 = xr[2 * lane + 1];
    float s  = a0.x + a0.y + a0.z + a0.w + a1.x + a1.y + a1.z + a1.w;
    float ss = a0.x * a0.x + a0.y * a0.y + a0.z * a0.z + a0.w * a0.w +
               a1.x * a1.x + a1.y * a1.y + a1.z * a1.z + a1.w * a1.w;
#pragma unroll
    for (int off = 32; off; off >>= 1) {
        s  += __shfl_xor(s, off);
        ss += __shfl_xor(ss, off);
    }
    const float mu = s * (1.f / 512.f);
    const float rs = rsqrtf(ss * (1.f / 512.f) - mu * mu + 1e-5f);
    const float4* gp = (const float4*)g;
    const float4* bpp = (const float4*)b;
    float4 g0 = gp[2 * lane], g1 = gp[2 * lane + 1];
    float4 b0 = bpp[2 * lane], b1 = bpp[2 * lane + 1];
    h8_t o;
    o[0] = (_Float16)((a0.x - mu) * rs * g0.x + b0.x);
    o[1] = (_Float16)((a0.y - mu) * rs * g0.y + b0.y);
    o[2] = (_Float16)((a0.z - mu) * rs * g0.z + b0.z);
    o[3] = (_Float16)((a0.w - mu) * rs * g0.w + b0.w);
    o[4] = (_Float16)((a1.x - mu) * rs * g1.x + b1.x);
    o[5] = (_Float16)((a1.y - mu) * rs * g1.y + b1.y);
    o[6] = (_Float16)((a1.z - mu) * rs * g1.z + b1.z);
    o[7] = (_Float16)((a1.w - mu) * rs * g1.w + b1.w);
    ((h8_t*)(y + row * CDIM))[lane] = o;
}

// ---------------------------------------------------------------------------
// Cast the 4 weight matrices (512x512 f32) to fp16. Wq gets *0.125 folded in.
// ---------------------------------------------------------------------------
__global__ __launch_bounds__(256) void cast_w4(const float* __restrict__ w0,
                                               const float* __restrict__ w1,
                                               const float* __restrict__ w2,
                                               const float* __restrict__ w3,
                                               _Float16* __restrict__ o) {
    const float* srcs[4] = {w0, w1, w2, w3};
    const float* w = srcs[blockIdx.y];
    const float scale = (blockIdx.y == 0) ? 0.125f : 1.0f;
    _Float16* dst = o + (size_t)blockIdx.y * (CDIM * CDIM);
    const int idx = blockIdx.x * 256 + threadIdx.x;  // 65536 float4 chunks
    float4 v = ((const float4*)w)[idx];
    h4_t ov = {(_Float16)(v.x * scale), (_Float16)(v.y * scale),
               (_Float16)(v.z * scale), (_Float16)(v.w * scale)};
    ((h4_t*)dst)[idx] = ov;
}

// ---------------------------------------------------------------------------
// Convert mask (128*256*256 f32) and pos (8*256*256 f32) to fp16. Shrinks the
// attention gather working set so the per-XCD 4MB L2 holds it (16 bp-masks
// x 128KB + 1MB pos ~= 3MB).
// mask: 1,048,576 h8 chunks -> blocks [0,4096); pos: 65,536 -> [4096,4352).
// ---------------------------------------------------------------------------
__global__ __launch_bounds__(256) void prep_hp(const float* __restrict__ mask,
                                               const float* __restrict__ pos,
                                               _Float16* __restrict__ maskh,
                                               _Float16* __restrict__ posh) {
    const size_t idx = (size_t)blockIdx.x * 256 + threadIdx.x;
    const float* src;
    _Float16* dst;
    size_t j;
    if (blockIdx.x < 4096) {
        src = mask; dst = maskh; j = idx;
    } else {
        src = pos; dst = posh; j = idx - (size_t)4096 * 256;
    }
    float4 a = ((const float4*)src)[2 * j];
    float4 b = ((const float4*)src)[2 * j + 1];
    h8_t o = {(_Float16)a.x, (_Float16)a.y, (_Float16)a.z, (_Float16)a.w,
              (_Float16)b.x, (_Float16)b.y, (_Float16)b.z, (_Float16)b.w};
    ((h8_t*)dst)[j] = o;
}

// ---------------------------------------------------------------------------
// GEMM (m97 structure): C[M=32768, 512] = A[32768,512] @ B^T, B = W[512,512]
// row-major (nn.Linear). 128x128 tile/block, BK=64, 4 waves each 64x64,
// 16x16x32 f16 MFMA.
// MODE 0: fp16 out, natural [row][col] layout.
// MODE 1: fp32 out + bias.
// MODE 2: fp16 out pre-transposed per head for attention V:
//         VT[(bp*8 + h)*64 + d][tok]
// ---------------------------------------------------------------------------
template <int MODE>
__global__ __launch_bounds__(256) void gemm_bt(const _Float16* __restrict__ A,
                                               const _Float16* __restrict__ Bw,
                                               _Float16* __restrict__ Ch,
                                               float* __restrict__ Cf,
                                               const float* __restrict__ bias) {
    constexpr int K = CDIM;
    __shared__ __align__(16) _Float16 As[128 * 64];
    __shared__ __align__(16) _Float16 Bs[128 * 64];
    const int t = threadIdx.x;
    const int wave = t >> 6, lane = t & 63;
    const int wm = wave & 1, wn = wave >> 1;
    const size_t rowBase = (size_t)blockIdx.x * 128;
    const int colBase = blockIdx.y * 128;

    f4_t acc[4][4] = {};

    const int srow = t >> 3;
    const int scol = (t & 7) * 8;
    const _Float16* Ap = A + (rowBase + srow) * K + scol;
    const _Float16* Bp = Bw + ((size_t)colBase + srow) * K + scol;
    char* AsB = (char*)As + wave * 1024;  // + c*4096, lane*16 added by HW
    char* BsB = (char*)Bs + wave * 1024;

    for (int k0 = 0; k0 < K; k0 += 64) {
#pragma unroll
        for (int c = 0; c < 4; ++c) {
            async16(Ap + (size_t)(32 * c) * K + k0, AsB + c * 4096);
            async16(Bp + (size_t)(32 * c) * K + k0, BsB + c * 4096);
        }
        __syncthreads();
#pragma unroll
        for (int kk = 0; kk < 64; kk += 32) {
            h8_t af[4], bf[4];
#pragma unroll
            for (int i = 0; i < 4; ++i)
                af[i] = *(const h8_t*)(As + (wm * 64 + i * 16 + (lane & 15)) * 64 +
                                       kk + (lane >> 4) * 8);
#pragma unroll
            for (int j = 0; j < 4; ++j)
                bf[j] = *(const h8_t*)(Bs + (wn * 64 + j * 16 + (lane & 15)) * 64 +
                                       kk + (lane >> 4) * 8);
#pragma unroll
            for (int i = 0; i < 4; ++i)
#pragma unroll
                for (int j = 0; j < 4; ++j)
                    acc[i][j] = __builtin_amdgcn_mfma_f32_16x16x32_f16(
                        af[i], bf[j], acc[i][j], 0, 0, 0);
        }
        __syncthreads();
    }
    // epilogue: C/D layout col=lane&15, row=(lane>>4)*4+reg  [m89/m91]
#pragma unroll
    for (int i = 0; i < 4; ++i) {
        const size_t growb = rowBase + wm * 64 + i * 16 + ((lane >> 4) * 4);
#pragma unroll
        for (int j = 0; j < 4; ++j) {
            const int gcol = colBase + wn * 64 + j * 16 + (lane & 15);
            if (MODE == 2) {
                const int bp = (int)(growb >> 8), tok = (int)(growb & 255);
                const int hh = gcol >> 6, dd = gcol & 63;
                h4_t w = {(_Float16)acc[i][j][0], (_Float16)acc[i][j][1],
                          (_Float16)acc[i][j][2], (_Float16)acc[i][j][3]};
                *(h4_t*)(Ch + ((size_t)(bp * NH + hh) * DH + dd) * NTOK + tok) = w;
            } else {
#pragma unroll
                for (int r = 0; r < 4; ++r) {
                    const size_t idx = (growb + r) * CDIM + gcol;
                    if (MODE == 0)
                        Ch[idx] = (_Float16)acc[i][j][r];
                    else
                        Cf[idx] = acc[i][j][r] + bias[gcol];
                }
            }
        }
    }
}

// ---------------------------------------------------------------------------
// MFMA flash attention, round-4 structure. Block = (bp,h), 4 waves; wave w
// owns Q rows [w*64, w*64+64). Per 64-j chunk: S^T = K Q^T (C/D col = i =
// lane&15 -> lane-uniform softmax stats), p = exp(mask*(s+pos)) with fp16
// mask/pos (Q pre-scaled 0.125), per-it P scratch -> B-operand, O^T += V^T P^T.
// Double-buffered K/VT chunks: 1 barrier per chunk (5 total). Per-it
// pipelining: mask/pos loads for it overlap S-MFMAs; P LDS round-trip is
// 16-row granular. LDS: 2*(9216+9216) + 9216 = 46080 B.
// ---------------------------------------------------------------------------
__global__ __launch_bounds__(256, 2) void attn_mfma2(
    const _Float16* __restrict__ Q, const _Float16* __restrict__ K,
    const _Float16* __restrict__ VT, const _Float16* __restrict__ maskh,
    const _Float16* __restrict__ posh, _Float16* __restrict__ O) {
    const int bp = blockIdx.x, h = blockIdx.y;
    const int t = threadIdx.x;
    const int wave = t >> 6, lane = t & 63;
    const int g = lane >> 4, li = lane & 15;

    __shared__ __align__(16) _Float16 Ks[2][64 * 72];   // [j in chunk][d]
    __shared__ __align__(16) _Float16 VTs[2][64 * 72];  // [d][j in chunk]
    __shared__ __align__(16) _Float16 Ps[4][16 * 72];   // per-wave per-it P

    // resident Q B-fragments: n=i=li, k=d = x*32+g*8+e
    h8_t qf[4][2];
#pragma unroll
    for (int it = 0; it < 4; ++it)
#pragma unroll
        for (int x = 0; x < 2; ++x)
            qf[it][x] = *(const h8_t*)(Q +
                (size_t)(bp * NTOK + wave * 64 + it * 16 + li) * CDIM +
                h * DH + x * 32 + g * 8);

    // staging: thread t handles K row (t>>2), 16 cols at (t&3)*16 of chunk
    const _Float16* Kg = K + ((size_t)(bp * NTOK) + (t >> 2)) * CDIM + h * DH +
                         (t & 3) * 16;
    const _Float16* Vg = VT + ((size_t)(bp * NH + h) * DH + (t >> 2)) * NTOK +
                         (t & 3) * 16;
    const int sOff = (t >> 2) * 72 + (t & 3) * 16;

    {   // preload chunk 0 -> buffer 0
        h8_t k0a = *(const h8_t*)(Kg);
        h8_t k0b = *(const h8_t*)(Kg + 8);
        h8_t v0a = *(const h8_t*)(Vg);
        h8_t v0b = *(const h8_t*)(Vg + 8);
        *(h8_t*)(&Ks[0][sOff]) = k0a;
        *(h8_t*)(&Ks[0][sOff + 8]) = k0b;
        *(h8_t*)(&VTs[0][sOff]) = v0a;
        *(h8_t*)(&VTs[0][sOff + 8]) = v0b;
    }

    f4_t o[4][4] = {};             // O^T tiles [dt][it]
    float lp[4] = {0.f, 0.f, 0.f, 0.f};
    __syncthreads();

#pragma unroll
    for (int c = 0; c < 4; ++c) {
        const int p = c & 1;
        // global prefetch of next chunk into registers
        h8_t kn0, kn1, vn0, vn1;
        if (c < 3) {
            kn0 = *(const h8_t*)(Kg + (size_t)(c + 1) * 64 * CDIM);
            kn1 = *(const h8_t*)(Kg + (size_t)(c + 1) * 64 * CDIM + 8);
            vn0 = *(const h8_t*)(Vg + (c + 1) * 64);
            vn1 = *(const h8_t*)(Vg + (c + 1) * 64 + 8);
        }
        // chunk-resident K / V^T fragments
        h8_t kf[4][2], vf[4][2];
#pragma unroll
        for (int jt = 0; jt < 4; ++jt)
#pragma unroll
            for (int x = 0; x < 2; ++x)
                kf[jt][x] = *(const h8_t*)(&Ks[p][(jt * 16 + li) * 72 + x * 32 + g * 8]);
#pragma unroll
        for (int dt = 0; dt < 4; ++dt)
#pragma unroll
            for (int x = 0; x < 2; ++x)
                vf[dt][x] = *(const h8_t*)(&VTs[p][(dt * 16 + li) * 72 + x * 32 + g * 8]);

#pragma unroll
        for (int it = 0; it < 4; ++it) {
            const int i = wave * 64 + it * 16 + li;
            const _Float16* mrow = maskh + (size_t)bp * (NTOK * NTOK) +
                                   (size_t)i * NTOK + c * 64 + g * 4;
            const _Float16* prow = posh + (size_t)h * (NTOK * NTOK) +
                                   (size_t)i * NTOK + c * 64 + g * 4;
            h4_t mm[4], pp[4];
#pragma unroll
            for (int jt = 0; jt < 4; ++jt) {
                mm[jt] = *(const h4_t*)(mrow + jt * 16);
                pp[jt] = *(const h4_t*)(prow + jt * 16);
            }
            // S^T tiles for this it
            f4_t s[4] = {};
#pragma unroll
            for (int x = 0; x < 2; ++x)
#pragma unroll
                for (int jt = 0; jt < 4; ++jt)
                    s[jt] = __builtin_amdgcn_mfma_f32_16x16x32_f16(
                        kf[jt][x], qf[it][x], s[jt], 0, 0, 0);
            // exp + pack -> per-wave P scratch (rows = li, cols = j)
            float lacc = 0.f;
#pragma unroll
            for (int jt = 0; jt < 4; ++jt) {
                float e0 = __expf((s[jt][0] + (float)pp[jt][0]) * (float)mm[jt][0]);
                float e1 = __expf((s[jt][1] + (float)pp[jt][1]) * (float)mm[jt][1]);
                float e2 = __expf((s[jt][2] + (float)pp[jt][2]) * (float)mm[jt][2]);
                float e3 = __expf((s[jt][3] + (float)pp[jt][3]) * (float)mm[jt][3]);
                lacc += (e0 + e1) + (e2 + e3);
                h4_t w = {(_Float16)e0, (_Float16)e1, (_Float16)e2, (_Float16)e3};
                *(h4_t*)(&Ps[wave][li * 72 + jt * 16 + g * 4]) = w;
            }
            lp[it] += lacc;
            // P^T B-fragments and PV
            h8_t pf0 = *(const h8_t*)(&Ps[wave][li * 72 + g * 8]);
            h8_t pf1 = *(const h8_t*)(&Ps[wave][li * 72 + 32 + g * 8]);
#pragma unroll
            for (int dt = 0; dt < 4; ++dt)
                o[dt][it] = __builtin_amdgcn_mfma_f32_16x16x32_f16(
                    vf[dt][0], pf0, o[dt][it], 0, 0, 0);
#pragma unroll
            for (int dt = 0; dt < 4; ++dt)
                o[dt][it] = __builtin_amdgcn_mfma_f32_16x16x32_f16(
                    vf[dt][1], pf1, o[dt][it], 0, 0, 0);
        }
        // stage next chunk into the alternate buffer
        if (c < 3) {
            *(h8_t*)(&Ks[1 - p][sOff]) = kn0;
            *(h8_t*)(&Ks[1 - p][sOff + 8]) = kn1;
            *(h8_t*)(&VTs[1 - p][sOff]) = vn0;
            *(h8_t*)(&VTs[1 - p][sOff + 8]) = vn1;
        }
        __syncthreads();
    }

    // epilogue: l per query col i (lane-uniform), divide, store fp16
    float inv[4];
#pragma unroll
    for (int it = 0; it < 4; ++it) {
        float l = lp[it];
        l += __shfl_xor(l, 16);
        l += __shfl_xor(l, 32);
        inv[it] = __builtin_amdgcn_rcpf(l);
    }
#pragma unroll
    for (int dt = 0; dt < 4; ++dt)
#pragma unroll
        for (int it = 0; it < 4; ++it) {
            const int i = wave * 64 + it * 16 + li;
            h4_t w = {(_Float16)(o[dt][it][0] * inv[it]),
                      (_Float16)(o[dt][it][1] * inv[it]),
                      (_Float16)(o[dt][it][2] * inv[it]),
                      (_Float16)(o[dt][it][3] * inv[it])};
            *(h4_t*)(O + (size_t)(bp * NTOK + i) * CDIM + h * DH + dt * 16 +
                     g * 4) = w;
        }
}

// ---------------------------------------------------------------------------
// ws layout (bytes):
//   [0, 32M)        XB   : LN'd input fp16 (reused per tensor, then attn out)
//   [32M, +2M)      WH   : Wq*0.125, Wk, Wv, Wo fp16
//   then QHp (32M), KHp (32M), VTg (32M), maskh (16.8M), posh (1M)  ~149MB
// ---------------------------------------------------------------------------
extern "C" void kernel_launch(void* const* d_in, const int* in_sizes, int n_in,
                              void* d_out, int out_size, void* d_ws, size_t ws_size,
                              hipStream_t stream) {
    const float* q    = (const float*)d_in[0];
    const float* k    = (const float*)d_in[1];
    const float* v    = (const float*)d_in[2];
    const float* mask = (const float*)d_in[3];
    const float* pos  = (const float*)d_in[4];
    const float* lnqg = (const float*)d_in[5];
    const float* lnqb = (const float*)d_in[6];
    const float* lnkg = (const float*)d_in[7];
    const float* lnkb = (const float*)d_in[8];
    const float* lnvg = (const float*)d_in[9];
    const float* lnvb = (const float*)d_in[10];
    const float* Wq   = (const float*)d_in[11];
    const float* Wk   = (const float*)d_in[12];
    const float* Wv   = (const float*)d_in[13];
    const float* Wo   = (const float*)d_in[14];
    const float* bo   = (const float*)d_in[15];
    float* out = (float*)d_out;

    char* ws = (char*)d_ws;
    const size_t XSZ = (size_t)ROWS * CDIM * sizeof(_Float16);  // 33554432
    _Float16* XB    = (_Float16*)ws;
    _Float16* WH    = (_Float16*)(ws + XSZ);
    _Float16* QHp   = (_Float16*)(ws + XSZ + 4 * (size_t)(CDIM * CDIM) * sizeof(_Float16));
    _Float16* KHp   = QHp + (size_t)ROWS * CDIM;
    _Float16* VTg   = KHp + (size_t)ROWS * CDIM;
    _Float16* maskh = VTg + (size_t)ROWS * CDIM;
    _Float16* posh  = maskh + (size_t)BP * NTOK * NTOK;

    cast_w4<<<dim3(256, 4), 256, 0, stream>>>(Wq, Wk, Wv, Wo, WH);
    prep_hp<<<4352, 256, 0, stream>>>(mask, pos, maskh, posh);

    ln_cast<<<8192, 256, 0, stream>>>(q, lnqg, lnqb, XB);
    gemm_bt<0><<<dim3(256, 4), 256, 0, stream>>>(XB, WH + 0 * (CDIM * CDIM), QHp, nullptr, nullptr);
    ln_cast<<<8192, 256, 0, stream>>>(k, lnkg, lnkb, XB);
    gemm_bt<0><<<dim3(256, 4), 256, 0, stream>>>(XB, WH + 1 * (CDIM * CDIM), KHp, nullptr, nullptr);
    ln_cast<<<8192, 256, 0, stream>>>(v, lnvg, lnvb, XB);
    gemm_bt<2><<<dim3(256, 4), 256, 0, stream>>>(XB, WH + 2 * (CDIM * CDIM), VTg, nullptr, nullptr);

    attn_mfma2<<<dim3(BP, NH), 256, 0, stream>>>(QHp, KHp, VTg, maskh, posh, XB);

    gemm_bt<1><<<dim3(256, 4), 256, 0, stream>>>(XB, WH + 3 * (CDIM * CDIM), nullptr, out, bo);
}